// Round 1
// 116.016 us; speedup vs baseline: 1.0310x; 1.0310x over previous
//
#include <hip/hip_runtime.h>
#include <math.h>

#define BB   1024
#define HH   256
#define NN   128
#define SS   2
#define RR   4
#define LOG2PI_F 1.8378770664093453f
#define DEV_MIN_F 0.001f
#define DEV_STEP_F 7.08661417322835e-05f   // (0.01-0.001)/127
#define LOG1P_HALF 0.40546510810816438f    // log1p(0.5)
#define SHIFT_F 12.0f                       // > max lb = -2ln(0.001)-log2pi = 11.98

#define OFF_GEN  524288
#define OFF_REAL 655360
#define OFF_A    786432
#define OFF_B    917504

typedef float f4_t __attribute__((ext_vector_type(4)));

#define FMA4(ACC, HS, WV)                                         \
    {                                                             \
        ACC.x = fmaf(HS, WV.x, ACC.x);                            \
        ACC.y = fmaf(HS, WV.y, ACC.y);                            \
        ACC.z = fmaf(HS, WV.z, ACC.z);                            \
        ACC.w = fmaf(HS, WV.w, ACC.w);                            \
    }

// Raw barrier: LDS-only ordering. Deliberately does NOT drain vmcnt, so
// prefetched weight loads stay in flight across the barrier (the compiler's
// __syncthreads always emits s_waitcnt vmcnt(0) lgkmcnt(0), killing any
// cross-barrier software pipeline). All barriers in this kernel order only
// LDS data; register-destined global loads are private and need no barrier.
#define BAR_LGKM() asm volatile("s_waitcnt lgkmcnt(0)\n\ts_barrier" ::: "memory")

// ---------------------------------------------------------------------------
// Wt[k*256 + 2n + c] = Wp[n*512 + 2k + c]; float2 granularity (half the
// instructions of the old scalar version). 128 blocks x 256 threads.
// ---------------------------------------------------------------------------
__global__ __launch_bounds__(256) void transpose_wp_kernel(
    const float* __restrict__ Wp, float* __restrict__ Wt) {
    const int t = threadIdx.x;
    const int k = blockIdx.x * 2 + (t >> 7);
    const int n = t & 127;
    const float2 v = ((const float2*)Wp)[n * 256 + k];
    *(float2*)&Wt[k * 256 + 2 * n] = v;
}

// ---------------------------------------------------------------------------
// Fused MLP + losses, 256 blocks x 1024 threads, 4 batch rows/block.
// MLP thread = (q = t>>6 == wave id: 16 K-slices of 16, c = t&63: col-quad).
// W (f4 loads, dwordx4) read exactly once per CU per layer; hb reads are
// wave-uniform b128 BROADCASTS (q == wave -> free).
// Partials: single-step — all 16 waves write part[16][4][256] (64 KB),
// one barrier, finalize thread (rL,j) sums 16 stride-1 b32 (conflict-free).
// NEW this round:
//  * raw lgkm-only barriers (no vmcnt drain at s_barrier)
//  * next-layer i=0 weight chunk (4 x f4) prefetched BEFORE the partial-write
//    barrier and consumed AFTER the finalize barrier -> L2 latency + stream
//    head overlaps the partial-write/finalize window of the previous layer.
//  * loss quad-gather in lane-relative order (slot k <-> point me^k): kills
//    the 24-cndmask normalization and the 8-shfl butterfly.
// ---------------------------------------------------------------------------
__global__ __launch_bounds__(1024, 4) void mlp_loss_kernel(
    const float* __restrict__ latents, const float* __restrict__ eps,
    const float* __restrict__ realPts, const float* __restrict__ predMu,
    const float* __restrict__ predScale,
    const float* __restrict__ W0, const float* __restrict__ b0,
    const float* __restrict__ W1, const float* __restrict__ b1,
    const float* __restrict__ W2, const float* __restrict__ b2,
    const float* __restrict__ W3, const float* __restrict__ b3,
    const float* __restrict__ W4, const float* __restrict__ b4,
    const float* __restrict__ Wt, const float* __restrict__ bp,
    float* __restrict__ out) {
    __shared__ __align__(16) float hb[RR][256];        // 4 KB activations
    __shared__ __align__(16) float part[16][RR][256];  // 64 KB partials
    __shared__ float2 sprm[NN];                        // 1 KB

    const int t  = threadIdx.x;
    const int q  = t >> 6;                // K-slice == wave id
    const int c  = t & 63;                // col-quad base j4 = 4c
    const int rL = t >> 8;                // row (finalize + loss)
    const int j  = t & 255;               // col (finalize + loss)
    const int brow = blockIdx.x * RR;

    if (t < NN) {
        float dv = DEV_MIN_F + (float)t * DEV_STEP_F;
        sprm[t] = make_float2(-0.5f / (dv * dv), -2.f * __logf(dv) - LOG2PI_F);
    }
    hb[rL][j] = latents[(brow + rL) * 256 + j];

    // biases in 6 VGPRs
    float biasv[6];
    biasv[0] = b0[j]; biasv[1] = b1[j]; biasv[2] = b2[j];
    biasv[3] = b3[j]; biasv[4] = b4[j]; biasv[5] = bp[j];

    // eps preloaded (needed immediately at loss start)
    const int nL = j >> 1, sL = j & 1;
    const int b = brow + rL;
    const float2 epv = ((const float2*)eps)[sL * (BB * NN) + b * NN + nL];

    const float* Wsrc[6] = {W0, W1, W2, W3, W4, Wt};
    const int woff = (q * 16) * 256 + 4 * c;

    // layer-0 i=0 chunk prefetch: in flight across the init barrier
    f4_t wpa, wpb, wpc, wpd;
    {
        const float* Wn = W0 + woff;
        wpa = *(const f4_t*)(Wn + 0 * 256);
        wpb = *(const f4_t*)(Wn + 1 * 256);
        wpc = *(const f4_t*)(Wn + 2 * 256);
        wpd = *(const f4_t*)(Wn + 3 * 256);
    }

    BAR_LGKM();

    #pragma unroll
    for (int L = 0; L < 6; ++L) {
        const float* __restrict__ Wb = Wsrc[L] + woff;
        f4_t acc[4];
        #pragma unroll
        for (int r = 0; r < 4; ++r) acc[r] = (f4_t)0.f;

        // i = 0: consume the prefetched chunk (vmcnt wait inserted here)
        {
            const int kb = q * 16;
            #pragma unroll
            for (int r = 0; r < 4; ++r) {
                f4_t hv = *(const f4_t*)&hb[r][kb];   // wave-uniform broadcast
                FMA4(acc[r], hv.x, wpa);
                FMA4(acc[r], hv.y, wpb);
                FMA4(acc[r], hv.z, wpc);
                FMA4(acc[r], hv.w, wpd);
            }
        }

        #pragma unroll
        for (int i = 1; i < 4; ++i) {
            f4_t w0 = *(const f4_t*)(Wb + (i * 4 + 0) * 256);
            f4_t w1 = *(const f4_t*)(Wb + (i * 4 + 1) * 256);
            f4_t w2 = *(const f4_t*)(Wb + (i * 4 + 2) * 256);
            f4_t w3 = *(const f4_t*)(Wb + (i * 4 + 3) * 256);
            const int kb = q * 16 + i * 4;
            #pragma unroll
            for (int r = 0; r < 4; ++r) {
                f4_t hv = *(const f4_t*)&hb[r][kb];   // wave-uniform broadcast
                FMA4(acc[r], hv.x, w0);
                FMA4(acc[r], hv.y, w1);
                FMA4(acc[r], hv.z, w2);
                FMA4(acc[r], hv.w, w3);
            }
        }

        // prefetch next layer's i=0 chunk; issued before the barrier asm
        // (memory clobber pins it), waited only at next layer's i=0 FMAs.
        if (L < 5) {
            const float* Wn = Wsrc[L + 1] + woff;
            wpa = *(const f4_t*)(Wn + 0 * 256);
            wpb = *(const f4_t*)(Wn + 1 * 256);
            wpc = *(const f4_t*)(Wn + 2 * 256);
            wpd = *(const f4_t*)(Wn + 3 * 256);
        }

        // single-step partial combine: every wave writes its own slot
        #pragma unroll
        for (int r = 0; r < 4; ++r)
            *(f4_t*)&part[q][r][4 * c] = acc[r];
        BAR_LGKM();

        // finalize: 16 stride-1 b32 reads (2 lanes/bank -> conflict-free)
        float v0 = part[0][rL][j]  + part[1][rL][j]  + part[2][rL][j]  + part[3][rL][j];
        float v1 = part[4][rL][j]  + part[5][rL][j]  + part[6][rL][j]  + part[7][rL][j];
        float v2 = part[8][rL][j]  + part[9][rL][j]  + part[10][rL][j] + part[11][rL][j];
        float v3 = part[12][rL][j] + part[13][rL][j] + part[14][rL][j] + part[15][rL][j];
        float val = (v0 + v1) + (v2 + v3);
        val += biasv[L];
        if (L == 5) val += 0.5f;
        else        val = fmaxf(val, 0.f);
        hb[rL][j] = val;   // safe: all hb broadcasts of this layer precede barrier-1
        BAR_LGKM();
    }

    // ---- loss phase: mu for row (brow+rL) in hb[rL] ----
    const float* __restrict__ muL = &hb[rL][0];
    const int n = nL, s = sL;
    const float devn = DEV_MIN_F + (float)n * DEV_STEP_F;
    const float2 prn = sprm[n];

    const float mux = muL[2 * n], muy = muL[2 * n + 1];
    const float px = fmaf(devn, epv.x, mux);
    const float py = fmaf(devn, epv.y, muy);

    ((float2*)out)[(size_t)(s * NN + n) * BB + b] = make_float2(px, py);

    // loss-tail inputs loaded here (softmax below hides the latency)
    const float2 pm = ((const float2*)predMu)[b];
    const float2 ps = ((const float2*)predScale)[b];
    const float2 rp = ((const float2*)realPts)[b];

    // quad gather, lane-relative order: slot k holds point (me ^ k).
    // No normalization selects needed; the combine below re-aligns.
    float PX0 = px,              PY0 = py;
    float PX1 = __shfl_xor(px, 1), PY1 = __shfl_xor(py, 1);
    float PX2 = __shfl_xor(px, 2), PY2 = __shfl_xor(py, 2);
    float PX3 = __shfl_xor(px, 3), PY3 = __shfl_xor(py, 3);

    // lane me scans modes {8*mi + 2*me, +1 : mi=0..15} for all 4 quad points
    const int me = t & 3;
    float S0 = 0.f, S1 = 0.f, S2 = 0.f, S3 = 0.f;
    #pragma unroll 4
    for (int mi = 0; mi < 16; ++mi) {
        f4_t mm = *(const f4_t*)&muL[16 * mi + 4 * me];
        f4_t pr = *(const f4_t*)((const float*)sprm + 16 * mi + 4 * me);
        float dx, dy, lb;
        dx = PX0 - mm.x; dy = PY0 - mm.y;
        lb = fmaf(fmaf(dx, dx, dy * dy), pr.x, pr.y); S0 += __expf(lb - SHIFT_F);
        dx = PX1 - mm.x; dy = PY1 - mm.y;
        lb = fmaf(fmaf(dx, dx, dy * dy), pr.x, pr.y); S1 += __expf(lb - SHIFT_F);
        dx = PX2 - mm.x; dy = PY2 - mm.y;
        lb = fmaf(fmaf(dx, dx, dy * dy), pr.x, pr.y); S2 += __expf(lb - SHIFT_F);
        dx = PX3 - mm.x; dy = PY3 - mm.y;
        lb = fmaf(fmaf(dx, dx, dy * dy), pr.x, pr.y); S3 += __expf(lb - SHIFT_F);
        dx = PX0 - mm.z; dy = PY0 - mm.w;
        lb = fmaf(fmaf(dx, dx, dy * dy), pr.z, pr.w); S0 += __expf(lb - SHIFT_F);
        dx = PX1 - mm.z; dy = PY1 - mm.w;
        lb = fmaf(fmaf(dx, dx, dy * dy), pr.z, pr.w); S1 += __expf(lb - SHIFT_F);
        dx = PX2 - mm.z; dy = PY2 - mm.w;
        lb = fmaf(fmaf(dx, dx, dy * dy), pr.z, pr.w); S2 += __expf(lb - SHIFT_F);
        dx = PX3 - mm.z; dy = PY3 - mm.w;
        lb = fmaf(fmaf(dx, dx, dy * dy), pr.z, pr.w); S3 += __expf(lb - SHIFT_F);
    }
    // combine: total denom for own point = own S0 + S1 from lane^1 (its slot1
    // is (me^1)^1 = me) + S2 from lane^2 + S3 from lane^3.
    float sum = S0 + __shfl_xor(S1, 1) + __shfl_xor(S2, 2) + __shfl_xor(S3, 3);
    (void)me;

    // diagonal closed-form: dx = devn*eps -> lb = prn.x*devn^2*|eps|^2 + prn.y
    float dxd = devn * epv.x, dyd = devn * epv.y;
    float lbd = fmaf(fmaf(dxd, dxd, dyd * dyd), prn.x, prn.y);
    float ed  = __expf(lbd - SHIFT_F);
    float diag = ed / sum;
    float lbv = (1.f - diag) * (1.f - diag);
    out[OFF_B + (size_t)b * (NN * SS) + j] = lbv;

    float zx = (px - pm.x) / ps.x, zy = (py - pm.y) / ps.y;
    float la = -0.5f * (zx * zx + zy * zy) - __logf(ps.x) - __logf(ps.y) - LOG2PI_F;
    float aa = 1.f / (1.f + __expf(la));
    float termA = LOG1P_HALF - log1pf(aa);
    termA = termA * termA;
    float gg = 1.f / (1.f + __expf(-la));

    float drx = rp.x - mux, dry = rp.y - muy;
    float lr = fmaf(fmaf(drx, drx, dry * dry), prn.x, prn.y);
    float rl = 1.f / (1.f + __expf(-lr));

    float termA_sum = termA + __shfl_xor(termA, 1);
    float gg_sum    = gg + __shfl_xor(gg, 1);
    if (s == 0) {
        out[OFF_GEN  + (size_t)b * NN + n] = 0.5f * gg_sum * (1.f - rl);
        out[OFF_REAL + (size_t)b * NN + n] = rl;
        out[OFF_A    + (size_t)b * NN + n] = 0.5f * termA_sum;
    }
}

// ---------------------------------------------------------------------------
extern "C" void kernel_launch(void* const* d_in, const int* in_sizes, int n_in,
                              void* d_out, int out_size, void* d_ws, size_t ws_size,
                              hipStream_t stream) {
    const float* latents   = (const float*)d_in[0];
    const float* realPts   = (const float*)d_in[1];
    const float* predMu    = (const float*)d_in[2];
    const float* predScale = (const float*)d_in[3];
    const float* eps       = (const float*)d_in[4];
    const float* W0 = (const float*)d_in[5];
    const float* b0 = (const float*)d_in[6];
    const float* W1 = (const float*)d_in[7];
    const float* b1 = (const float*)d_in[8];
    const float* W2 = (const float*)d_in[9];
    const float* b2 = (const float*)d_in[10];
    const float* W3 = (const float*)d_in[11];
    const float* b3 = (const float*)d_in[12];
    const float* W4 = (const float*)d_in[13];
    const float* b4 = (const float*)d_in[14];
    const float* Wp = (const float*)d_in[15];
    const float* bp = (const float*)d_in[16];

    float* Wtp = (float*)d_ws;  // 256 KB

    transpose_wp_kernel<<<dim3(128), dim3(256), 0, stream>>>(Wp, Wtp);
    mlp_loss_kernel<<<dim3(BB / RR), dim3(1024), 0, stream>>>(
        latents, eps, realPts, predMu, predScale,
        W0, b0, W1, b1, W2, b2, W3, b3, W4, b4, Wtp, bp, (float*)d_out);
}

// Round 2
// 115.567 us; speedup vs baseline: 1.0350x; 1.0039x over previous
//
#include <hip/hip_runtime.h>
#include <math.h>

#define BB   1024
#define HH   256
#define NN   128
#define SS   2
#define RR   4
#define LOG2PI_F 1.8378770664093453f
#define DEV_MIN_F 0.001f
#define DEV_STEP_F 7.08661417322835e-05f   // (0.01-0.001)/127
#define LOG1P_HALF 0.40546510810816438f    // log1p(0.5)
#define SHIFT_F 12.0f                       // > max lb = -2ln(0.001)-log2pi = 11.98
#define L2E_F       1.4426950408889634f     // log2(e)
#define SHIFT_L2E_F 17.312340490667561f     // SHIFT * log2(e)
#define NHALF_L2E_F -0.7213475204444817f    // -0.5 * log2(e)
#define LOG2PI_L2E_F 2.6514961294723187f    // LOG2PI * log2(e)

#define OFF_GEN  524288
#define OFF_REAL 655360
#define OFF_A    786432
#define OFF_B    917504

typedef float f4_t __attribute__((ext_vector_type(4)));

#define FMA4(ACC, HS, WV)                                         \
    {                                                             \
        ACC.x = fmaf(HS, WV.x, ACC.x);                            \
        ACC.y = fmaf(HS, WV.y, ACC.y);                            \
        ACC.z = fmaf(HS, WV.z, ACC.z);                            \
        ACC.w = fmaf(HS, WV.w, ACC.w);                            \
    }

// Raw barrier: LDS-only ordering; does NOT drain vmcnt, so weight prefetches
// stay in flight across it. All barriers here order only LDS data.
#define BAR_LGKM() asm volatile("s_waitcnt lgkmcnt(0)\n\ts_barrier" ::: "memory")

__device__ __forceinline__ float fast_exp2(float x) {
#if __has_builtin(__builtin_amdgcn_exp2f)
    return __builtin_amdgcn_exp2f(x);   // raw v_exp_f32 (exp2)
#else
    return exp2f(x);
#endif
}
__device__ __forceinline__ float fast_log2(float x) {
#if __has_builtin(__builtin_amdgcn_logf)
    return __builtin_amdgcn_logf(x);    // raw v_log_f32 (log2)
#else
    return log2f(x);
#endif
}

// ---------------------------------------------------------------------------
// Wt[k*256 + 2n + c] = Wp[n*512 + 2k + c]; float2 granularity.
// ---------------------------------------------------------------------------
__global__ __launch_bounds__(256) void transpose_wp_kernel(
    const float* __restrict__ Wp, float* __restrict__ Wt) {
    const int t = threadIdx.x;
    const int k = blockIdx.x * 2 + (t >> 7);
    const int n = t & 127;
    const float2 v = ((const float2*)Wp)[n * 256 + k];
    *(float2*)&Wt[k * 256 + 2 * n] = v;
}

// ---------------------------------------------------------------------------
// Fused MLP + losses, 256 blocks x 1024 threads, 4 batch rows/block.
// MLP thread = (q = wave id: K-slice of 16, c = t&63: col-quad).
// NEW this round:
//  * deep load pipeline: all 12 non-prefetched weight chunks issued at layer
//    start (w[12]); i=0 consumed from cross-barrier prefetch; next-layer
//    prefetch issued right after i=0 (regs dead) -> in flight across i1-3 +
//    partial-write + finalize + both barriers.
//  * sampled stores staged in LDS (reusing dead `part`), written coalesced
//    as float4 (32 B segments, was 64x 8 B scattered lines per wave + RMW).
//  * softmax in exp2 domain: sprm pre-scaled by log2(e) with SHIFT folded
//    (saves 1 mul per exp term); gg = 1 - aa (exact, saves exp+rcp);
//    la in log2 domain via v_log_f32/v_exp_f32.
// ---------------------------------------------------------------------------
__global__ __launch_bounds__(1024, 4) void mlp_loss_kernel(
    const float* __restrict__ latents, const float* __restrict__ eps,
    const float* __restrict__ realPts, const float* __restrict__ predMu,
    const float* __restrict__ predScale,
    const float* __restrict__ W0, const float* __restrict__ b0,
    const float* __restrict__ W1, const float* __restrict__ b1,
    const float* __restrict__ W2, const float* __restrict__ b2,
    const float* __restrict__ W3, const float* __restrict__ b3,
    const float* __restrict__ W4, const float* __restrict__ b4,
    const float* __restrict__ Wt, const float* __restrict__ bp,
    float* __restrict__ out) {
    __shared__ __align__(16) float hb[RR][256];        // 4 KB activations
    __shared__ __align__(16) float part[16][RR][256];  // 64 KB partials
    __shared__ float2 sprm[NN];                        // 1 KB

    const int t  = threadIdx.x;
    const int q  = t >> 6;                // K-slice == wave id
    const int c  = t & 63;                // col-quad base j4 = 4c
    const int rL = t >> 8;                // row (finalize + loss)
    const int j  = t & 255;               // col (finalize + loss)
    const int brow = blockIdx.x * RR;

    if (t < NN) {
        float dv = DEV_MIN_F + (float)t * DEV_STEP_F;
        float a  = -0.5f / (dv * dv);
        float bb_ = fmaf(-2.f, __logf(dv), -LOG2PI_F);
        // exp2-domain, SHIFT folded: term = exp2(fma(d2, x, y))
        sprm[t] = make_float2(a * L2E_F, (bb_ - SHIFT_F) * L2E_F);
    }
    hb[rL][j] = latents[(brow + rL) * 256 + j];

    // biases in 6 VGPRs
    float biasv[6];
    biasv[0] = b0[j]; biasv[1] = b1[j]; biasv[2] = b2[j];
    biasv[3] = b3[j]; biasv[4] = b4[j]; biasv[5] = bp[j];

    // eps preloaded (needed immediately at loss start)
    const int nL = j >> 1, sL = j & 1;
    const int b = brow + rL;
    const float2 epv = ((const float2*)eps)[sL * (BB * NN) + b * NN + nL];

    const float* Wsrc[6] = {W0, W1, W2, W3, W4, Wt};
    const int woff = (q * 16) * 256 + 4 * c;

    // layer-0 i=0 chunk prefetch: in flight across the init barrier
    f4_t wpa, wpb, wpc, wpd;
    {
        const float* Wn = W0 + woff;
        wpa = *(const f4_t*)(Wn + 0 * 256);
        wpb = *(const f4_t*)(Wn + 1 * 256);
        wpc = *(const f4_t*)(Wn + 2 * 256);
        wpd = *(const f4_t*)(Wn + 3 * 256);
    }

    BAR_LGKM();

    #pragma unroll
    for (int L = 0; L < 6; ++L) {
        const float* __restrict__ Wb = Wsrc[L] + woff;

        // issue the whole remainder of the layer NOW (12 b128 in flight,
        // behind the 4 already-prefetched chunks)
        f4_t w[12];
        #pragma unroll
        for (int u = 0; u < 12; ++u)
            w[u] = *(const f4_t*)(Wb + (4 + u) * 256);

        f4_t acc[4];
        #pragma unroll
        for (int r = 0; r < 4; ++r) acc[r] = (f4_t)0.f;

        // i = 0: consume the prefetched chunk (waits only on those 4 loads)
        {
            const int kb = q * 16;
            #pragma unroll
            for (int r = 0; r < 4; ++r) {
                f4_t hv = *(const f4_t*)&hb[r][kb];   // wave-uniform broadcast
                FMA4(acc[r], hv.x, wpa);
                FMA4(acc[r], hv.y, wpb);
                FMA4(acc[r], hv.z, wpc);
                FMA4(acc[r], hv.w, wpd);
            }
        }

        // wp regs are dead now: issue next layer's head immediately so it is
        // in flight across i1-3 FMAs, partial write, finalize, both barriers.
        if (L < 5) {
            const float* Wn = Wsrc[L + 1] + woff;
            wpa = *(const f4_t*)(Wn + 0 * 256);
            wpb = *(const f4_t*)(Wn + 1 * 256);
            wpc = *(const f4_t*)(Wn + 2 * 256);
            wpd = *(const f4_t*)(Wn + 3 * 256);
        }

        #pragma unroll
        for (int i = 1; i < 4; ++i) {
            const int kb = q * 16 + i * 4;
            #pragma unroll
            for (int r = 0; r < 4; ++r) {
                f4_t hv = *(const f4_t*)&hb[r][kb];   // wave-uniform broadcast
                FMA4(acc[r], hv.x, w[(i - 1) * 4 + 0]);
                FMA4(acc[r], hv.y, w[(i - 1) * 4 + 1]);
                FMA4(acc[r], hv.z, w[(i - 1) * 4 + 2]);
                FMA4(acc[r], hv.w, w[(i - 1) * 4 + 3]);
            }
        }

        // single-step partial combine: every wave writes its own slot
        #pragma unroll
        for (int r = 0; r < 4; ++r)
            *(f4_t*)&part[q][r][4 * c] = acc[r];
        BAR_LGKM();

        // finalize: 16 stride-1 b32 reads (2 lanes/bank -> conflict-free)
        float v0 = part[0][rL][j]  + part[1][rL][j]  + part[2][rL][j]  + part[3][rL][j];
        float v1 = part[4][rL][j]  + part[5][rL][j]  + part[6][rL][j]  + part[7][rL][j];
        float v2 = part[8][rL][j]  + part[9][rL][j]  + part[10][rL][j] + part[11][rL][j];
        float v3 = part[12][rL][j] + part[13][rL][j] + part[14][rL][j] + part[15][rL][j];
        float val = (v0 + v1) + (v2 + v3);
        val += biasv[L];
        if (L == 5) val += 0.5f;
        else        val = fmaxf(val, 0.f);
        hb[rL][j] = val;   // safe: all hb broadcasts of this layer precede barrier-1
        BAR_LGKM();
    }

    // ---- loss phase: mu for row (brow+rL) in hb[rL] ----
    const float* __restrict__ muL = &hb[rL][0];
    const int n = nL, s = sL;
    const float devn = DEV_MIN_F + (float)n * DEV_STEP_F;
    const float2 prn = sprm[n];   // exp2-domain, SHIFT folded

    const float mux = muL[2 * n], muy = muL[2 * n + 1];
    const float px = fmaf(devn, epv.x, mux);
    const float py = fmaf(devn, epv.y, muy);

    // stage sampled in LDS (part is dead); coalesced global write after the
    // softmax hides the barrier.
    float2* samp = (float2*)&part[0][0][0];    // [s][n][r], 8 KB
    samp[(s * NN + n) * RR + rL] = make_float2(px, py);

    // loss-tail inputs loaded here (softmax below hides the latency)
    const float2 pm = ((const float2*)predMu)[b];
    const float2 ps = ((const float2*)predScale)[b];
    const float2 rp = ((const float2*)realPts)[b];

    // quad gather, lane-relative order: slot k holds point (me ^ k).
    float PX0 = px,                PY0 = py;
    float PX1 = __shfl_xor(px, 1), PY1 = __shfl_xor(py, 1);
    float PX2 = __shfl_xor(px, 2), PY2 = __shfl_xor(py, 2);
    float PX3 = __shfl_xor(px, 3), PY3 = __shfl_xor(py, 3);

    // lane me scans modes {8*mi + 2*me, +1 : mi=0..15} for all 4 quad points
    const int me = t & 3;
    float S0 = 0.f, S1 = 0.f, S2 = 0.f, S3 = 0.f;
    #pragma unroll 4
    for (int mi = 0; mi < 16; ++mi) {
        f4_t mm = *(const f4_t*)&muL[16 * mi + 4 * me];
        f4_t pr = *(const f4_t*)((const float*)sprm + 16 * mi + 4 * me);
        float dx, dy;
        dx = PX0 - mm.x; dy = PY0 - mm.y;
        S0 += fast_exp2(fmaf(fmaf(dx, dx, dy * dy), pr.x, pr.y));
        dx = PX1 - mm.x; dy = PY1 - mm.y;
        S1 += fast_exp2(fmaf(fmaf(dx, dx, dy * dy), pr.x, pr.y));
        dx = PX2 - mm.x; dy = PY2 - mm.y;
        S2 += fast_exp2(fmaf(fmaf(dx, dx, dy * dy), pr.x, pr.y));
        dx = PX3 - mm.x; dy = PY3 - mm.y;
        S3 += fast_exp2(fmaf(fmaf(dx, dx, dy * dy), pr.x, pr.y));
        dx = PX0 - mm.z; dy = PY0 - mm.w;
        S0 += fast_exp2(fmaf(fmaf(dx, dx, dy * dy), pr.z, pr.w));
        dx = PX1 - mm.z; dy = PY1 - mm.w;
        S1 += fast_exp2(fmaf(fmaf(dx, dx, dy * dy), pr.z, pr.w));
        dx = PX2 - mm.z; dy = PY2 - mm.w;
        S2 += fast_exp2(fmaf(fmaf(dx, dx, dy * dy), pr.z, pr.w));
        dx = PX3 - mm.z; dy = PY3 - mm.w;
        S3 += fast_exp2(fmaf(fmaf(dx, dx, dy * dy), pr.z, pr.w));
    }
    // combine: own denom = own S0 + S1 from lane^1 + S2 from lane^2 + S3 from lane^3
    float sum = S0 + __shfl_xor(S1, 1) + __shfl_xor(S2, 2) + __shfl_xor(S3, 3);

    // diagonal closed-form (same exp2-shifted domain -> shift cancels in ratio)
    float dxd = devn * epv.x, dyd = devn * epv.y;
    float ed  = fast_exp2(fmaf(fmaf(dxd, dxd, dyd * dyd), prn.x, prn.y));
    float diag = ed / sum;
    float lbv = (1.f - diag) * (1.f - diag);
    out[OFF_B + (size_t)b * (NN * SS) + j] = lbv;

    // la in log2 domain: la2 = la*log2e
    float zx = (px - pm.x) / ps.x, zy = (py - pm.y) / ps.y;
    float la2 = fmaf(fmaf(zx, zx, zy * zy), NHALF_L2E_F,
                     -(fast_log2(ps.x) + fast_log2(ps.y)) - LOG2PI_L2E_F);
    float aa = 1.f / (1.f + fast_exp2(la2));   // sigmoid(-la)
    float gg = 1.f - aa;                        // sigmoid(la), exact identity
    float termA = LOG1P_HALF - log1pf(aa);
    termA = termA * termA;

    // rl = sigmoid(lr); lr2 = (lr - SHIFT)*log2e -> exp(-lr) = exp2(-lr2 - SHIFT*log2e)
    float drx = rp.x - mux, dry = rp.y - muy;
    float lr2 = fmaf(fmaf(drx, drx, dry * dry), prn.x, prn.y);
    float rl = 1.f / (1.f + fast_exp2(-lr2 - SHIFT_L2E_F));

    float termA_sum = termA + __shfl_xor(termA, 1);
    float gg_sum    = gg + __shfl_xor(gg, 1);
    if (s == 0) {
        out[OFF_GEN  + (size_t)b * NN + n] = 0.5f * gg_sum * (1.f - rl);
        out[OFF_REAL + (size_t)b * NN + n] = rl;
        out[OFF_A    + (size_t)b * NN + n] = 0.5f * termA_sum;
    }

    // coalesced sampled write: 512 threads x float4 (two b-rows each);
    // 32 B segments instead of 64 scattered 8 B lines per wave.
    BAR_LGKM();
    if (t < 512) {
        const int sn = t >> 1, rp2 = t & 1;
        f4_t v = *(const f4_t*)&samp[sn * RR + rp2 * 2];
        *(f4_t*)&((float2*)out)[(size_t)sn * BB + brow + rp2 * 2] = v;
    }
}

// ---------------------------------------------------------------------------
extern "C" void kernel_launch(void* const* d_in, const int* in_sizes, int n_in,
                              void* d_out, int out_size, void* d_ws, size_t ws_size,
                              hipStream_t stream) {
    const float* latents   = (const float*)d_in[0];
    const float* realPts   = (const float*)d_in[1];
    const float* predMu    = (const float*)d_in[2];
    const float* predScale = (const float*)d_in[3];
    const float* eps       = (const float*)d_in[4];
    const float* W0 = (const float*)d_in[5];
    const float* b0 = (const float*)d_in[6];
    const float* W1 = (const float*)d_in[7];
    const float* b1 = (const float*)d_in[8];
    const float* W2 = (const float*)d_in[9];
    const float* b2 = (const float*)d_in[10];
    const float* W3 = (const float*)d_in[11];
    const float* b3 = (const float*)d_in[12];
    const float* W4 = (const float*)d_in[13];
    const float* b4 = (const float*)d_in[14];
    const float* Wp = (const float*)d_in[15];
    const float* bp = (const float*)d_in[16];

    float* Wtp = (float*)d_ws;  // 256 KB

    transpose_wp_kernel<<<dim3(128), dim3(256), 0, stream>>>(Wp, Wtp);
    mlp_loss_kernel<<<dim3(BB / RR), dim3(1024), 0, stream>>>(
        latents, eps, realPts, predMu, predScale,
        W0, b0, W1, b1, W2, b2, W3, b3, W4, b4, Wtp, bp, (float*)d_out);
}